// Round 12
// baseline (188.924 us; speedup 1.0000x reference)
//
#include <hip/hip_runtime.h>
#include <hip/hip_bf16.h>
#include <float.h>

#define N_PRED 8192
#define M_TGT  16384
#define KD     128
#define TOPK   5
#define SPLITS 32
#define MSPLIT (M_TGT / SPLITS)            // 512 targets per split
#define TILE_T 64                          // targets per LDS tile -> 33.3 KB LDS
#define NTILES (MSPLIT / TILE_T)           // 8
#define ROWS_PER_BLOCK 256                 // 8 waves x 32 rows
#define ROWBLKS (N_PRED / ROWS_PER_BLOCK)  // 32 -> grid 1024 = 4 blocks/CU, 32 waves/CU
#define NBLKROW (SPLITS * 16)              // 512 (col,split) blocks per row, 32 tgt each
#define FIN_BLOCKS 512                     // finalize grid: 2 rows per wave

using short8  = __attribute__((ext_vector_type(8))) short;
using floatx4 = __attribute__((ext_vector_type(4))) float;

__device__ __forceinline__ unsigned short f2bf(float v) {
    unsigned int u = __float_as_uint(v);
    u = (u + 0x7FFFu + ((u >> 16) & 1u)) >> 16;
    return (unsigned short)u;
}

// async global->LDS, dest = wave-uniform base + lane*size
__device__ __forceinline__ void async16(const void* g, void* l) {
    __builtin_amdgcn_global_load_lds(
        (const __attribute__((address_space(1))) unsigned int*)g,
        (__attribute__((address_space(3))) unsigned int*)l, 16, 0, 0);
}
__device__ __forceinline__ void async4(const void* g, void* l) {
    __builtin_amdgcn_global_load_lds(
        (const __attribute__((address_space(1))) unsigned int*)g,
        (__attribute__((address_space(3))) unsigned int*)l, 4, 0, 0);
}

// sorted ascending top-5 insert: 4x v_med3_f32 + 1x v_min_f32
__device__ __forceinline__ void ins5(float* t, float d) {
    t[4] = __builtin_amdgcn_fmed3f(d, t[3], t[4]);
    t[3] = __builtin_amdgcn_fmed3f(d, t[2], t[3]);
    t[2] = __builtin_amdgcn_fmed3f(d, t[1], t[2]);
    t[1] = __builtin_amdgcn_fmed3f(d, t[0], t[1]);
    t[0] = fminf(t[0], d);
}

// 64-lane butterfly merge of sorted-5 lists (all lanes end with global top-5)
__device__ __forceinline__ void bmerge(float* u) {
    #pragma unroll
    for (int off = 1; off < 64; off <<= 1) {
        float o0 = __shfl_xor(u[0], off);
        float o1 = __shfl_xor(u[1], off);
        float o2 = __shfl_xor(u[2], off);
        float o3 = __shfl_xor(u[3], off);
        float o4 = __shfl_xor(u[4], off);
        ins5(u, o0); ins5(u, o1); ins5(u, o2); ins5(u, o3); ins5(u, o4);
    }
}

// bf16x2 dword pair dot (both operands packed bf16): 4 unpack + 2 fma
__device__ __forceinline__ float dotd(unsigned int p, unsigned int t) {
    const float plo = __uint_as_float(p << 16);
    const float phi = __uint_as_float(p & 0xFFFF0000u);
    const float tlo = __uint_as_float(t << 16);
    const float thi = __uint_as_float(t & 0xFFFF0000u);
    return plo * tlo + phi * thi;
}

// ---- prep: bf16 casts (pred pre-scaled by -2), fp32 norms, zero acc/counter -
__global__ void prep_kernel(const float* __restrict__ pred,
                            const float* __restrict__ tgt,
                            unsigned short* __restrict__ predB,
                            unsigned short* __restrict__ tgtB,
                            float* __restrict__ a2,
                            float* __restrict__ b2,
                            float* __restrict__ acc,
                            unsigned int* __restrict__ counter) {
    const int row = blockIdx.x * 8 + (threadIdx.x >> 5);
    const int l32 = threadIdx.x & 31;
    const float* src;
    unsigned short* dst;
    float scale;
    float* norm;
    if (row < N_PRED) {
        src = pred + (size_t)row * KD;
        dst = predB + (size_t)row * KD;
        scale = -2.0f;                    // fold "-2 a.b" into A
        norm = a2 + row;
    } else {
        const int rr = row - N_PRED;
        src = tgt + (size_t)rr * KD;
        dst = tgtB + (size_t)rr * KD;
        scale = 1.0f;
        norm = b2 + rr;
    }
    const float4 x = reinterpret_cast<const float4*>(src)[l32];
    uint2 p;
    p.x = (unsigned int)f2bf(x.x * scale) | ((unsigned int)f2bf(x.y * scale) << 16);
    p.y = (unsigned int)f2bf(x.z * scale) | ((unsigned int)f2bf(x.w * scale) << 16);
    reinterpret_cast<uint2*>(dst)[l32] = p;
    float s = x.x * x.x + x.y * x.y + x.z * x.z + x.w * x.w;  // fp32 norms
    #pragma unroll
    for (int off = 16; off > 0; off >>= 1) s += __shfl_down(s, off, 32);
    if (l32 == 0) norm[0] = s;
    if (blockIdx.x == 0 && threadIdx.x == 0) { acc[0] = 0.0f; counter[0] = 0u; }
}

// ---- main: R2's proven inner loop (VGPR 52); TILE_T=64, grid 1024 -----------
// Occupancy lever (R11 analysis): 66.5KB LDS capped residency at 2 blocks/CU
// (~10 waves/CU time-avg, MfmaUtil 29%, no pipe >50%).  TILE_T=64 -> 33.3KB
// LDS (R7-proven allocation) x SPLITS=32 -> grid 1024 = 4 blocks/CU =
// 32 waves/CU.  Inner loop, insert, staging pattern byte-identical per
// iteration; only NTILES/g-count per block change.  Split->XCD pinning kept
// (32 = 0 mod 8: all blocks of a split land on XCD split%8, 4 splits/XCD,
// 524KB L2-resident).  Selection blocks shrink to 32 targets (512/row):
// flag rate ~2% of rows, rescan = one 32-dot half-wave (R10's granularity
// lesson applied in the cheap direction).
__global__ __launch_bounds__(512, 4) void density_kernel(
        const unsigned short* __restrict__ predB,
        const unsigned short* __restrict__ tgtB,
        const float* __restrict__ b2,
        float2* __restrict__ wsMin) {   // [row][split][col] = (t1,t2)
    const int tid   = threadIdx.x;
    const int wave  = tid >> 6;
    const int lane  = tid & 63;
    const int col   = lane & 15;
    const int quad  = lane >> 4;
    const int split = blockIdx.x & (SPLITS - 1);  // same-XCD blocks share B chunks
    const int rowblk = blockIdx.x >> 5;
    const int r0 = rowblk * ROWS_PER_BLOCK + wave * 32;
    const int m0 = split * MSPLIT;

    __shared__ short8 frag[2][TILE_T * 16];   // [buf][(g*4+kf)*64 + lane] : 32 KB
    __shared__ float  b2s[2][TILE_T];         // 512 B

    // A fragments for 2 row-sets of 16: A[m=lane&15][k=quad*8+j]
    short8 afrag[2][4];
    #pragma unroll
    for (int rf = 0; rf < 2; rf++)
        #pragma unroll
        for (int kf = 0; kf < 4; kf++)
            afrag[rf][kf] = *reinterpret_cast<const short8*>(
                predB + (size_t)(r0 + rf * 16 + col) * KD + kf * 32 + quad * 8);

    // sorted top-2 (x = min, y = 2nd min) per (rf,rg) block
    float2 bm[2][4];
    #pragma unroll
    for (int rf = 0; rf < 2; rf++)
        #pragma unroll
        for (int rg = 0; rg < 4; rg++)
            bm[rf][rg] = make_float2(FLT_MAX, FLT_MAX);

    // stage tile 0: 16 KB, 2 async16 per wave (8 waves cover 16 chunks)
    {
        #pragma unroll
        for (int s = 0; s < 2; ++s) {
            const int ci = wave * 2 + s, g = ci >> 2, kf = ci & 3;
            const unsigned short* src =
                tgtB + (size_t)(m0 + g * 16 + col) * KD + kf * 32 + quad * 8;
            async16(src, &frag[0][ci * 64]);
        }
        if (wave == 0) async4(b2 + m0 + lane, &b2s[0][0]);
    }
    __syncthreads();

    for (int t = 0; t < NTILES; ++t) {
        const int cur = t & 1;
        if (t + 1 < NTILES) {                 // stage next tile (async)
            const int m0t = m0 + (t + 1) * TILE_T;
            #pragma unroll
            for (int s = 0; s < 2; ++s) {
                const int ci = wave * 2 + s, g = ci >> 2, kf = ci & 3;
                const unsigned short* src =
                    tgtB + (size_t)(m0t + g * 16 + col) * KD + kf * 32 + quad * 8;
                async16(src, &frag[cur ^ 1][ci * 64]);
            }
            if (wave == 0) async4(b2 + m0t + lane, &b2s[cur ^ 1][0]);
        }

        #pragma unroll
        for (int g = 0; g < 4; ++g) {
            const float bq = b2s[cur][g * 16 + col];
            short8 bf[4];
            #pragma unroll
            for (int kf = 0; kf < 4; ++kf)
                bf[kf] = frag[cur][(g * 4 + kf) * 64 + lane];  // sequential ds_read_b128
            const floatx4 ci = {bq, bq, bq, bq};   // b^2 seed, shared by both rf
            #pragma unroll
            for (int rf = 0; rf < 2; ++rf) {
                floatx4 c;
                c = __builtin_amdgcn_mfma_f32_16x16x32_bf16(afrag[rf][0], bf[0], ci, 0, 0, 0);
                c = __builtin_amdgcn_mfma_f32_16x16x32_bf16(afrag[rf][1], bf[1], c, 0, 0, 0);
                c = __builtin_amdgcn_mfma_f32_16x16x32_bf16(afrag[rf][2], bf[2], c, 0, 0, 0);
                c = __builtin_amdgcn_mfma_f32_16x16x32_bf16(afrag[rf][3], bf[3], c, 0, 0, 0);
                #pragma unroll
                for (int rg = 0; rg < 4; ++rg) {   // sorted-2 insert: 2 ops/elem
                    const float d = c[rg];
                    bm[rf][rg].y = __builtin_amdgcn_fmed3f(d, bm[rf][rg].x, bm[rf][rg].y);
                    bm[rf][rg].x = fminf(bm[rf][rg].x, d);
                }
            }
        }
        __syncthreads();   // drains staging vmcnt; 3 co-resident blocks cover
    }

    // store per-lane top-2 pairs; no cross-lane merge needed here
    #pragma unroll
    for (int rf = 0; rf < 2; ++rf)
        #pragma unroll
        for (int rg = 0; rg < 4; ++rg) {
            const int row = r0 + rf * 16 + quad * 4 + rg;
            wsMin[((size_t)row * SPLITS + split) * 16 + col] = bm[rf][rg];
        }
}

// ---- finalize: exact top-5 from per-block top-2 + rare rescan, hinge, sum ---
// Lane owns 8 blocks (512/row, 32 targets each).  Flag rate ~C(5,2)/512 ~ 2%
// of rows; rescan = one 32-target half-wave dot pass per flagged block.
// R9-proven last-block protocol (atomics, no fence).
__global__ __launch_bounds__(512) void finalize_kernel(
        const float2* __restrict__ wsMin,
        const unsigned short* __restrict__ predB,
        const unsigned short* __restrict__ tgtB,
        const float* __restrict__ b2,
        const float* __restrict__ a2,
        float* __restrict__ acc,
        unsigned int* __restrict__ counter,
        float* __restrict__ out) {
    const int wave = threadIdx.x >> 6;
    const int lane = threadIdx.x & 63;

    float wsum = 0.0f;   // redundant across lanes (u is lane-uniform after bmerge)
    #pragma unroll 1
    for (int i = 0; i < 2; ++i) {
        const int row = (blockIdx.x * 8 + wave) * 2 + i;

        // lane owns blocks 8*lane .. 8*lane+7 (block id b = split*16 + col)
        const float2* pv = wsMin + (size_t)row * NBLKROW + lane * 8;
        float2 v[8];
        #pragma unroll
        for (int j = 0; j < 8; ++j) v[j] = pv[j];

        float u[5] = {FLT_MAX, FLT_MAX, FLT_MAX, FLT_MAX, FLT_MAX};
        #pragma unroll
        for (int j = 0; j < 8; ++j) { ins5(u, v[j].x); ins5(u, v[j].y); }
        bmerge(u);
        const float m5 = u[4];

        // block can hide a 3rd top-5 element only if its t2 <= m5
        unsigned long long fl[8];
        unsigned long long any = 0ull;
        #pragma unroll
        for (int j = 0; j < 8; ++j) { fl[j] = __ballot(v[j].y <= m5); any |= fl[j]; }

        if (any) {
            // rebuild winners excluding flagged blocks entirely, then merge
            // their fully-rescanned 32 values (exact; no double counting)
            #pragma unroll
            for (int j = 0; j < 8; ++j)
                if (v[j].y <= m5) { v[j].x = FLT_MAX; v[j].y = FLT_MAX; }
            #pragma unroll
            for (int j = 0; j < 5; ++j) u[j] = FLT_MAX;
            #pragma unroll
            for (int j = 0; j < 8; ++j) { ins5(u, v[j].x); ins5(u, v[j].y); }
            bmerge(u);
            #pragma unroll
            for (int j = 0; j < 8; ++j) {
                unsigned long long m = fl[j];  // wave-uniform ballot -> no divergence
                while (m) {
                    const int bit = __ffsll((unsigned long long)m) - 1;
                    m &= m - 1;
                    const int blk = bit * 8 + j;
                    const int sp = blk >> 4, cb = blk & 15;
                    // block targets: sp*MSPLIT + k*16 + cb, k=0..31 (lanes 0-31)
                    float s = FLT_MAX;
                    if (lane < 32) {
                        const int tg = sp * MSPLIT + lane * 16 + cb;
                        s = b2[tg];
                        const uint4* tp = reinterpret_cast<const uint4*>(tgtB + (size_t)tg * KD);
                        const uint4* pp = reinterpret_cast<const uint4*>(predB + (size_t)row * KD);
                        #pragma unroll
                        for (int q = 0; q < 16; ++q) {
                            const uint4 pa = pp[q], tb = tp[q];
                            s += dotd(pa.x, tb.x) + dotd(pa.y, tb.y)
                               + dotd(pa.z, tb.z) + dotd(pa.w, tb.w);
                        }
                    }
                    float w[5] = {s, FLT_MAX, FLT_MAX, FLT_MAX, FLT_MAX};
                    bmerge(w);                 // top-5 of the block's 32 values
                    #pragma unroll
                    for (int q = 0; q < 5; ++q) ins5(u, w[q]);
                }
            }
        }

        const float a = a2[row];
        #pragma unroll
        for (int j = 0; j < 5; ++j) {
            const float dd = sqrtf(fmaxf(u[j] + a, 0.0f));
            wsum += fmaxf(dd - 1.0f, 0.0f);
        }
    }

    __shared__ float hsum[8];
    if (lane == 0) hsum[wave] = wsum;
    __syncthreads();
    if (threadIdx.x == 0) {
        float tot = 0.0f;
        #pragma unroll
        for (int w = 0; w < 8; ++w) tot += hsum[w];
        atomicAdd(acc, tot);
        const unsigned int done = atomicAdd(counter, 1u);
        if (done == gridDim.x - 1) {
            const float t = atomicAdd(acc, 0.0f);   // atomic read: full sum
            out[0] = t * (1.0f / (float)(N_PRED * TOPK));
        }
    }
}

extern "C" void kernel_launch(void* const* d_in, const int* in_sizes, int n_in,
                              void* d_out, int out_size, void* d_ws, size_t ws_size,
                              hipStream_t stream) {
    const float* pred = (const float*)d_in[0];
    const float* tgt  = (const float*)d_in[1];
    char* ws = (char*)d_ws;
    // ws: predB 2MB @0 | tgtB 4MB @2M | a2 32KB @6M | b2 64KB @6M+32K |
    //     acc/counter @6M+96K | wsMin 32MB @6M+128K  (total ~38.4 MB)
    unsigned short* predB = (unsigned short*)(ws);
    unsigned short* tgtB  = (unsigned short*)(ws + (size_t)2 * 1024 * 1024);
    float* a2     = (float*)(ws + (size_t)6 * 1024 * 1024);
    float* b2     = (float*)(ws + (size_t)6 * 1024 * 1024 + 32 * 1024);
    float* acc    = (float*)(ws + (size_t)6 * 1024 * 1024 + 96 * 1024);
    unsigned int* counter = (unsigned int*)(ws + (size_t)6 * 1024 * 1024 + 96 * 1024 + 64);
    float2* wsMin = (float2*)(ws + (size_t)6 * 1024 * 1024 + 128 * 1024);
    float* out = (float*)d_out;

    prep_kernel<<<(N_PRED + M_TGT) / 8, 256, 0, stream>>>(pred, tgt, predB, tgtB, a2, b2, acc, counter);
    density_kernel<<<ROWBLKS * SPLITS, 512, 0, stream>>>(predB, tgtB, b2, wsMin);
    finalize_kernel<<<FIN_BLOCKS, 512, 0, stream>>>(wsMin, predB, tgtB, b2, a2, acc, counter, out);
}

// Round 13
// 125.495 us; speedup vs baseline: 1.5054x; 1.5054x over previous
//
#include <hip/hip_runtime.h>
#include <hip/hip_bf16.h>
#include <float.h>

#define N_PRED 8192
#define M_TGT  16384
#define KD     128
#define TOPK   5
#define SPLITS 16
#define MSPLIT (M_TGT / SPLITS)            // 1024 targets per split
#define TILE_T 128                         // targets per LDS tile
#define NTILES (MSPLIT / TILE_T)           // 8
#define ROWS_PER_BLOCK 256                 // 8 waves x 32 rows
#define ROWBLKS (N_PRED / ROWS_PER_BLOCK)  // 32 -> grid 512, 2 blocks/CU
#define NBLKROW (SPLITS * 16)              // 256 (col,split) blocks per row
#define FIN_BLOCKS 512                     // finalize grid: 2 rows per wave

using short8  = __attribute__((ext_vector_type(8))) short;
using floatx4 = __attribute__((ext_vector_type(4))) float;

__device__ __forceinline__ unsigned short f2bf(float v) {
    unsigned int u = __float_as_uint(v);
    u = (u + 0x7FFFu + ((u >> 16) & 1u)) >> 16;
    return (unsigned short)u;
}

// async global->LDS, dest = wave-uniform base + lane*size
__device__ __forceinline__ void async16(const void* g, void* l) {
    __builtin_amdgcn_global_load_lds(
        (const __attribute__((address_space(1))) unsigned int*)g,
        (__attribute__((address_space(3))) unsigned int*)l, 16, 0, 0);
}
__device__ __forceinline__ void async4(const void* g, void* l) {
    __builtin_amdgcn_global_load_lds(
        (const __attribute__((address_space(1))) unsigned int*)g,
        (__attribute__((address_space(3))) unsigned int*)l, 4, 0, 0);
}

// sorted ascending top-5 insert: 4x v_med3_f32 + 1x v_min_f32
__device__ __forceinline__ void ins5(float* t, float d) {
    t[4] = __builtin_amdgcn_fmed3f(d, t[3], t[4]);
    t[3] = __builtin_amdgcn_fmed3f(d, t[2], t[3]);
    t[2] = __builtin_amdgcn_fmed3f(d, t[1], t[2]);
    t[1] = __builtin_amdgcn_fmed3f(d, t[0], t[1]);
    t[0] = fminf(t[0], d);
}

// 64-lane butterfly merge of sorted-5 lists (all lanes end with global top-5)
__device__ __forceinline__ void bmerge(float* u) {
    #pragma unroll
    for (int off = 1; off < 64; off <<= 1) {
        float o0 = __shfl_xor(u[0], off);
        float o1 = __shfl_xor(u[1], off);
        float o2 = __shfl_xor(u[2], off);
        float o3 = __shfl_xor(u[3], off);
        float o4 = __shfl_xor(u[4], off);
        ins5(u, o0); ins5(u, o1); ins5(u, o2); ins5(u, o3); ins5(u, o4);
    }
}

// bf16x2 dword pair dot (both operands packed bf16): 4 unpack + 2 fma
__device__ __forceinline__ float dotd(unsigned int p, unsigned int t) {
    const float plo = __uint_as_float(p << 16);
    const float phi = __uint_as_float(p & 0xFFFF0000u);
    const float tlo = __uint_as_float(t << 16);
    const float thi = __uint_as_float(t & 0xFFFF0000u);
    return plo * tlo + phi * thi;
}

// ---- prep: bf16 casts (pred pre-scaled by -2), fp32 norms, zero acc/counter -
__global__ void prep_kernel(const float* __restrict__ pred,
                            const float* __restrict__ tgt,
                            unsigned short* __restrict__ predB,
                            unsigned short* __restrict__ tgtB,
                            float* __restrict__ a2,
                            float* __restrict__ b2,
                            float* __restrict__ acc,
                            unsigned int* __restrict__ counter) {
    const int row = blockIdx.x * 8 + (threadIdx.x >> 5);
    const int l32 = threadIdx.x & 31;
    const float* src;
    unsigned short* dst;
    float scale;
    float* norm;
    if (row < N_PRED) {
        src = pred + (size_t)row * KD;
        dst = predB + (size_t)row * KD;
        scale = -2.0f;                    // fold "-2 a.b" into A
        norm = a2 + row;
    } else {
        const int rr = row - N_PRED;
        src = tgt + (size_t)rr * KD;
        dst = tgtB + (size_t)rr * KD;
        scale = 1.0f;
        norm = b2 + rr;
    }
    const float4 x = reinterpret_cast<const float4*>(src)[l32];
    uint2 p;
    p.x = (unsigned int)f2bf(x.x * scale) | ((unsigned int)f2bf(x.y * scale) << 16);
    p.y = (unsigned int)f2bf(x.z * scale) | ((unsigned int)f2bf(x.w * scale) << 16);
    reinterpret_cast<uint2*>(dst)[l32] = p;
    float s = x.x * x.x + x.y * x.y + x.z * x.z + x.w * x.w;  // fp32 norms
    #pragma unroll
    for (int off = 16; off > 0; off >>= 1) s += __shfl_down(s, off, 32);
    if (l32 == 0) norm[0] = s;
    if (blockIdx.x == 0 && threadIdx.x == 0) { acc[0] = 0.0f; counter[0] = 0u; }
}

// ---- main: proven optimum of this structure (44.5 us, VGPR 52, absmax 0) ----
// SESSION FLOOR NOTES (final):
//  * NRF=2 @ 8 waves, TILE_T=128, grid 512 is the measured optimum.  All
//    geometry variants regressed or spilled: NRF=4 (R4/R7: 48us), TILE_T=256
//    (R3: failed), grid 1024 (R12: VGPR cap 64 -> 490MB scratch, 122us).
//  * Toolchain hazard: __launch_bounds__ 2nd arg >= 4 caps VGPR at 64.  This
//    body's natural 52 fits; ANY restructuring of the staging/loops can push
//    natural pressure past 64 and spill catastrophically (R5/R6/R12).
//  * Selection: sorted top-2 per (col,split) 64-target block = 2 VALU
//    ops/element (5x cheaper than streaming top-5); exact recovery in
//    finalize.  Granularity is optimal: coarser blocks (R10) cost +17us in
//    rescan work.
//  * Occupancy is NOT the lever: clean 16-waves/CU runs (R7) showed zero
//    gain -- the barrier-synced global_load_lds structure is issue-limited
//    per wave (MfmaUtil ~29%), not latency-limited.
__global__ __launch_bounds__(512, 4) void density_kernel(
        const unsigned short* __restrict__ predB,
        const unsigned short* __restrict__ tgtB,
        const float* __restrict__ b2,
        float2* __restrict__ wsMin) {   // [row][split][col] = (t1,t2)
    const int tid   = threadIdx.x;
    const int wave  = tid >> 6;
    const int lane  = tid & 63;
    const int col   = lane & 15;
    const int quad  = lane >> 4;
    const int split = blockIdx.x & (SPLITS - 1);  // same-XCD blocks share B chunks
    const int rowblk = blockIdx.x >> 4;
    const int r0 = rowblk * ROWS_PER_BLOCK + wave * 32;
    const int m0 = split * MSPLIT;

    __shared__ short8 frag[2][TILE_T * 16];   // [buf][(g*4+kf)*64 + lane] : 64 KB
    __shared__ float  b2s[2][TILE_T];         // 1 KB

    // A fragments for 2 row-sets of 16: A[m=lane&15][k=quad*8+j]
    short8 afrag[2][4];
    #pragma unroll
    for (int rf = 0; rf < 2; rf++)
        #pragma unroll
        for (int kf = 0; kf < 4; kf++)
            afrag[rf][kf] = *reinterpret_cast<const short8*>(
                predB + (size_t)(r0 + rf * 16 + col) * KD + kf * 32 + quad * 8);

    // sorted top-2 (x = min, y = 2nd min) per (rf,rg) block
    float2 bm[2][4];
    #pragma unroll
    for (int rf = 0; rf < 2; rf++)
        #pragma unroll
        for (int rg = 0; rg < 4; rg++)
            bm[rf][rg] = make_float2(FLT_MAX, FLT_MAX);

    // stage tile 0: 32 KB, 4 async16 per wave
    {
        #pragma unroll
        for (int s = 0; s < 4; ++s) {
            const int ci = wave * 4 + s, g = ci >> 2, kf = ci & 3;
            const unsigned short* src =
                tgtB + (size_t)(m0 + g * 16 + col) * KD + kf * 32 + quad * 8;
            async16(src, &frag[0][ci * 64]);
        }
        if (wave < 2) async4(b2 + m0 + wave * 64 + lane, &b2s[0][wave * 64]);
    }
    __syncthreads();

    for (int t = 0; t < NTILES; ++t) {
        const int cur = t & 1;
        if (t + 1 < NTILES) {                 // stage next tile (async)
            const int m0t = m0 + (t + 1) * TILE_T;
            #pragma unroll
            for (int s = 0; s < 4; ++s) {
                const int ci = wave * 4 + s, g = ci >> 2, kf = ci & 3;
                const unsigned short* src =
                    tgtB + (size_t)(m0t + g * 16 + col) * KD + kf * 32 + quad * 8;
                async16(src, &frag[cur ^ 1][ci * 64]);
            }
            if (wave < 2) async4(b2 + m0t + wave * 64 + lane, &b2s[cur ^ 1][wave * 64]);
        }

        #pragma unroll
        for (int g = 0; g < 8; ++g) {
            const float bq = b2s[cur][g * 16 + col];
            short8 bf[4];
            #pragma unroll
            for (int kf = 0; kf < 4; ++kf)
                bf[kf] = frag[cur][(g * 4 + kf) * 64 + lane];  // sequential ds_read_b128
            const floatx4 ci = {bq, bq, bq, bq};   // b^2 seed, shared by both rf
            #pragma unroll
            for (int rf = 0; rf < 2; ++rf) {
                floatx4 c;
                c = __builtin_amdgcn_mfma_f32_16x16x32_bf16(afrag[rf][0], bf[0], ci, 0, 0, 0);
                c = __builtin_amdgcn_mfma_f32_16x16x32_bf16(afrag[rf][1], bf[1], c, 0, 0, 0);
                c = __builtin_amdgcn_mfma_f32_16x16x32_bf16(afrag[rf][2], bf[2], c, 0, 0, 0);
                c = __builtin_amdgcn_mfma_f32_16x16x32_bf16(afrag[rf][3], bf[3], c, 0, 0, 0);
                #pragma unroll
                for (int rg = 0; rg < 4; ++rg) {   // sorted-2 insert: 2 ops/elem
                    const float d = c[rg];
                    bm[rf][rg].y = __builtin_amdgcn_fmed3f(d, bm[rf][rg].x, bm[rf][rg].y);
                    bm[rf][rg].x = fminf(bm[rf][rg].x, d);
                }
            }
        }
        __syncthreads();   // drains staging vmcnt; co-resident block covers
    }

    // store per-lane top-2 pairs; no cross-lane merge needed here
    #pragma unroll
    for (int rf = 0; rf < 2; ++rf)
        #pragma unroll
        for (int rg = 0; rg < 4; ++rg) {
            const int row = r0 + rf * 16 + quad * 4 + rg;
            wsMin[((size_t)row * SPLITS + split) * 16 + col] = bm[rf][rg];
        }
}

// ---- finalize: exact top-5 from per-block top-2 + rare rescan, hinge, sum ---
// 3-launch pipeline: final reduction folded in via last-block protocol
// (atomicAdd acc + counter; NO __threadfence -- same-address atomics are
// device-scope ordered, so the last block's atomic read sees all 512
// contributions).  R1 measured the fence (not the atomics) at ~18us/1024blk.
__global__ __launch_bounds__(512) void finalize_kernel(
        const float2* __restrict__ wsMin,
        const unsigned short* __restrict__ predB,
        const unsigned short* __restrict__ tgtB,
        const float* __restrict__ b2,
        const float* __restrict__ a2,
        float* __restrict__ acc,
        unsigned int* __restrict__ counter,
        float* __restrict__ out) {
    const int wave = threadIdx.x >> 6;
    const int lane = threadIdx.x & 63;

    float wsum = 0.0f;   // redundant across lanes (u is lane-uniform after bmerge)
    #pragma unroll 1
    for (int i = 0; i < 2; ++i) {
        const int row = (blockIdx.x * 8 + wave) * 2 + i;

        // lane owns blocks 4*lane .. 4*lane+3 (block id b = split*16 + col)
        const float2* pv = wsMin + (size_t)row * NBLKROW + lane * 4;
        float2 v[4];
        #pragma unroll
        for (int j = 0; j < 4; ++j) v[j] = pv[j];

        float u[5] = {FLT_MAX, FLT_MAX, FLT_MAX, FLT_MAX, FLT_MAX};
        #pragma unroll
        for (int j = 0; j < 4; ++j) { ins5(u, v[j].x); ins5(u, v[j].y); }
        bmerge(u);
        const float m5 = u[4];

        // block can hide a 3rd top-5 element only if its t2 <= m5
        unsigned long long fl[4];
        #pragma unroll
        for (int j = 0; j < 4; ++j) fl[j] = __ballot(v[j].y <= m5);

        if (fl[0] | fl[1] | fl[2] | fl[3]) {
            // rebuild winners excluding flagged blocks entirely, then merge
            // their fully-rescanned 64 values (exact; no double counting)
            #pragma unroll
            for (int j = 0; j < 4; ++j)
                if (v[j].y <= m5) { v[j].x = FLT_MAX; v[j].y = FLT_MAX; }
            #pragma unroll
            for (int j = 0; j < 5; ++j) u[j] = FLT_MAX;
            #pragma unroll
            for (int j = 0; j < 4; ++j) { ins5(u, v[j].x); ins5(u, v[j].y); }
            bmerge(u);
            #pragma unroll
            for (int j = 0; j < 4; ++j) {
                unsigned long long m = fl[j];  // wave-uniform ballot -> no divergence
                while (m) {
                    const int bit = __ffsll((unsigned long long)m) - 1;
                    m &= m - 1;
                    const int blk = bit * 4 + j;
                    const int sp = blk >> 4, cb = blk & 15;
                    // block targets: sp*MSPLIT + k*16 + cb, k=0..63 (one per lane)
                    const int tg = sp * MSPLIT + lane * 16 + cb;
                    float s = b2[tg];
                    const uint4* tp = reinterpret_cast<const uint4*>(tgtB + (size_t)tg * KD);
                    const uint4* pp = reinterpret_cast<const uint4*>(predB + (size_t)row * KD);
                    #pragma unroll
                    for (int q = 0; q < 16; ++q) {
                        const uint4 pa = pp[q], tb = tp[q];
                        s += dotd(pa.x, tb.x) + dotd(pa.y, tb.y)
                           + dotd(pa.z, tb.z) + dotd(pa.w, tb.w);
                    }
                    float w[5] = {s, FLT_MAX, FLT_MAX, FLT_MAX, FLT_MAX};
                    bmerge(w);                 // top-5 of the block's 64 values
                    #pragma unroll
                    for (int q = 0; q < 5; ++q) ins5(u, w[q]);
                }
            }
        }

        const float a = a2[row];
        #pragma unroll
        for (int j = 0; j < 5; ++j) {
            const float dd = sqrtf(fmaxf(u[j] + a, 0.0f));
            wsum += fmaxf(dd - 1.0f, 0.0f);
        }
    }

    __shared__ float hsum[8];
    if (lane == 0) hsum[wave] = wsum;
    __syncthreads();
    if (threadIdx.x == 0) {
        float tot = 0.0f;
        #pragma unroll
        for (int w = 0; w < 8; ++w) tot += hsum[w];
        atomicAdd(acc, tot);
        const unsigned int done = atomicAdd(counter, 1u);
        if (done == gridDim.x - 1) {
            const float t = atomicAdd(acc, 0.0f);   // atomic read: full sum
            out[0] = t * (1.0f / (float)(N_PRED * TOPK));
        }
    }
}

extern "C" void kernel_launch(void* const* d_in, const int* in_sizes, int n_in,
                              void* d_out, int out_size, void* d_ws, size_t ws_size,
                              hipStream_t stream) {
    const float* pred = (const float*)d_in[0];
    const float* tgt  = (const float*)d_in[1];
    char* ws = (char*)d_ws;
    // ws: predB 2MB @0 | tgtB 4MB @2M | a2 32KB @6M | b2 64KB @6M+32K |
    //     acc/counter @6M+96K | wsMin 16MB @6M+128K  (total ~22.3 MB)
    unsigned short* predB = (unsigned short*)(ws);
    unsigned short* tgtB  = (unsigned short*)(ws + (size_t)2 * 1024 * 1024);
    float* a2     = (float*)(ws + (size_t)6 * 1024 * 1024);
    float* b2     = (float*)(ws + (size_t)6 * 1024 * 1024 + 32 * 1024);
    float* acc    = (float*)(ws + (size_t)6 * 1024 * 1024 + 96 * 1024);
    unsigned int* counter = (unsigned int*)(ws + (size_t)6 * 1024 * 1024 + 96 * 1024 + 64);
    float2* wsMin = (float2*)(ws + (size_t)6 * 1024 * 1024 + 128 * 1024);
    float* out = (float*)d_out;

    prep_kernel<<<(N_PRED + M_TGT) / 8, 256, 0, stream>>>(pred, tgt, predB, tgtB, a2, b2, acc, counter);
    density_kernel<<<ROWBLKS * SPLITS, 512, 0, stream>>>(predB, tgtB, b2, wsMin);
    finalize_kernel<<<FIN_BLOCKS, 512, 0, stream>>>(wsMin, predB, tgtB, b2, a2, acc, counter, out);
}